// Round 7
// baseline (357.043 us; speedup 1.0000x reference)
//
#include <hip/hip_runtime.h>
#include <hip/hip_bf16.h>
#include <stdint.h>

// ---------------------------------------------------------------------------
// FusionNet: seq[t,d] = sum_r w[r]*(imu1[t]@A[r,:,d])*(vid1[t]@Bv[r,:,d]) + fb[d]
//            out[t]   = (relu(seq@W1 + b1) @ W2 + b2) / (anthro0*anthro1)
//
// History:
//  R0 (153us): 16x16x32 MFMA, LDS tables, 512thr/(512,2), 1 blk/CU, 20% occ.
//  R1-R5: occupancy/persistent-loop attempts -> VGPR budget collapse or
//      unroll explosion -> spills (WRITE_SIZE 55-726MB). Lessons: 2nd
//      launch_bounds arg is min-BLOCKS/CU; no multi-tile loops.
//  R6 (130us): swapped MFMA (acc=[rank][token]) cut shfl chains 8x. -23us,
//      matching the "8 serial blocks x wave-chain" latency model.
//  R7: LDS (89.9KB) caps at 1 block/CU regardless -> (512,1) raises VGPR
//      budget to 256 FOR FREE. Spend it on 32x32x16 MFMA: 32 tokens/wave,
//      per-token MFMA count halved (and 4096 vs 3378 FLOP/cy), ds_reads
//      halved, rank-reduce = 7 in-lane adds + 1 shfl per 2 d's (7x fewer
//      cross-lane ops/token), 1024 blocks -> 4 serial blocks/CU (staging
//      amortized 2x). Layouts: C/D row=(reg&3)+8*(reg>>2)+4*hi col=lane&31
//      (HW-verified); A/B lane=(k>>3)*32+row, j=k&7 (mirror of the
//      16x16x32 map this kernel family has been passing with).
// ---------------------------------------------------------------------------

#define NTOK   262144      // B*S = 64*4096
#define FDIM   128
#define RANKN  16
#define FUSED  10
#define WTE    (FUSED*RANKN*FDIM)   // 20480 bf16 elements per weight table
#define NEXTRA 1984        // f32: a0 160 | b0 160 | W1L 1280 | b1L 128 | w20 128 | w21 128

typedef unsigned short u16;
typedef __bf16 bf16x8 __attribute__((ext_vector_type(8)));
typedef float  f32x4  __attribute__((ext_vector_type(4)));
typedef float  f32x16 __attribute__((ext_vector_type(16)));

static __device__ __forceinline__ u16 f2bf(float f) {
    union { float f; uint32_t u; } c; c.f = f;
    uint32_t u = c.u + 0x7FFFu + ((c.u >> 16) & 1u);   // RNE
    return (u16)(u >> 16);
}

// ---------------------------------------------------------------------------
// Prep: bf16 weight tables in 32x32x16 MFMA A-fragment order:
//   table[((nt*8+ks)*64+lane)*8+j] = Wmod[k][col],
//     k = ks*16 + (lane>>5)*8 + j   (K=128 over 8 ksteps)
//     col = nt*32 + (lane&31);  col -> d = nt*2 + (col>>4), r = col&15
//   Wimu[k][col] = fw[r]*imu_factor[r,0,k+1,d];  Wvid: vid_factor.
// Extras (f32):
//   a0/b0[nt*32 + dl*16 + hi*8 + slot] = const row, rank=(slot&3)+8*(slot>>2)+4*hi
//   W1L[((hi*16+jg)*10+d)*4+i] = W1[d][hi*64+jg*4+i]
//   b1L/w20/w21[(hi*16+jg)*4+i]: b1'=b1+fb@W1, W2 columns
// ---------------------------------------------------------------------------
__global__ void prep_kernel(const float* __restrict__ imf, const float* __restrict__ vif,
                            const float* __restrict__ fw,  const float* __restrict__ fb,
                            const float* __restrict__ W1,  const float* __restrict__ b1,
                            const float* __restrict__ W2,
                            u16* __restrict__ wImu, u16* __restrict__ wVid,
                            float* __restrict__ extra) {
    int idx = blockIdx.x * blockDim.x + threadIdx.x;
    float* a0  = extra;
    float* b0  = extra + 160;
    float* W1L = extra + 320;
    float* b1L = extra + 1600;
    float* w20 = extra + 1728;
    float* w21 = extra + 1856;

    if (idx < FUSED * RANKN * FDIM) {           // 20480 fragment elements
        int j    = idx & 7;
        int lane = (idx >> 3) & 63;
        int ks   = (idx >> 9) & 7;
        int nt   = idx >> 12;                   // 0..4
        int k    = ks * 16 + (lane >> 5) * 8 + j;
        int col  = nt * 32 + (lane & 31);
        int d    = nt * 2 + ((col >> 4) & 1);
        int r    = col & 15;
        int src  = r * ((FDIM + 1) * FUSED) + (k + 1) * FUSED + d;
        wImu[idx] = f2bf(fw[r] * imf[src]);
        wVid[idx] = f2bf(vif[src]);
    }
    if (idx < 160) {                            // a0/b0 in acc-reg order
        int slot = idx & 7;
        int hi   = (idx >> 3) & 1;
        int dl   = (idx >> 4) & 1;
        int nt   = idx >> 5;
        int d    = nt * 2 + dl;
        int r    = (slot & 3) + 8 * (slot >> 2) + 4 * hi;
        int src  = r * ((FDIM + 1) * FUSED) + d;
        a0[idx] = fw[r] * imf[src];
        b0[idx] = vif[src];
    }
    if (idx < 1280) {                           // W1L[(gq*10+d)*4+i]
        int i  = idx & 3;
        int t  = idx >> 2;
        int d  = t % 10;
        int gq = t / 10;                        // 0..31
        int hi = gq >> 4, jg = gq & 15;
        int j  = hi * 64 + jg * 4 + i;
        W1L[idx] = W1[d * FDIM + j];
    }
    if (idx < FDIM) {                           // b1L / w20 / w21 in gq order
        int i  = idx & 3;
        int gq = idx >> 2;
        int hi = gq >> 4, jg = gq & 15;
        int j  = hi * 64 + jg * 4 + i;
        float acc = b1[j];
        #pragma unroll
        for (int d = 0; d < FUSED; ++d) acc += fb[d] * W1[d * FDIM + j];
        b1L[idx] = acc;
        w20[idx] = W2[2 * j];
        w21[idx] = W2[2 * j + 1];
    }
}

// ---------------------------------------------------------------------------
// Main: 512 threads = 8 waves, each wave owns 32 tokens. (512,1): LDS caps
// at 1 block/CU anyway, so take the full 256-VGPR budget (no spill possible).
// ---------------------------------------------------------------------------
__launch_bounds__(512, 1)
__global__ void fusion_main(const float* __restrict__ imu, const float* __restrict__ vid,
                            const float* __restrict__ anthro,
                            const u16* __restrict__ wImuG, const u16* __restrict__ wVidG,
                            const float* __restrict__ extraG,
                            const float* __restrict__ b2g,
                            float* __restrict__ out) {
    extern __shared__ char smem[];
    u16* sFI = (u16*)smem;                // [5 nt][8 ks][64 lane][8] bf16
    u16* sFV = sFI + WTE;
    float* sX   = (float*)(sFV + WTE);
    float* sA0  = sX;                     // [5 nt][2 dl][2 hi][8 slot]
    float* sB0  = sX + 160;
    float* sW1L = sX + 320;               // [32 gq][10 d][4]
    float* sB1L = sX + 1600;              // [32 gq][4]
    float* sW20 = sX + 1728;
    float* sW21 = sX + 1856;

    // ---- stage to LDS (coalesced uint4 copies) ----
    {
        const uint4* srcI = (const uint4*)wImuG;
        const uint4* srcV = (const uint4*)wVidG;
        const uint4* srcX = (const uint4*)extraG;
        uint4* dstI = (uint4*)sFI;
        uint4* dstV = (uint4*)sFV;
        uint4* dstX = (uint4*)sX;
        for (int i = threadIdx.x; i < WTE / 8; i += blockDim.x) {  // 2560
            dstI[i] = srcI[i];
            dstV[i] = srcV[i];
        }
        for (int i = threadIdx.x; i < NEXTRA / 4; i += blockDim.x) // 496
            dstX[i] = srcX[i];
    }

    const int lane = threadIdx.x & 63;
    const int hi   = lane >> 5;          // K-half / j-half / acc-row bit
    const int col  = lane & 31;          // token index within wave tile
    const int wid  = threadIdx.x >> 6;
    const int t0   = (blockIdx.x * 8 + wid) * 32;   // 32 tokens per wave

    const int bidx = t0 >> 12;           // S = 4096, 32 | 4096
    const float invwh = 1.0f / (anthro[2 * bidx] * anthro[2 * bidx + 1]);
    const float b20 = b2g[0], b21 = b2g[1];

    // ---- token fragments (B operand): lane holds T[n=col][k=ks*16+hi*8+j]
    bf16x8 tI[8], tV[8];
    {
        const float* baseI = imu + (size_t)(t0 + col) * FDIM + hi * 8;
        const float* baseV = vid + (size_t)(t0 + col) * FDIM + hi * 8;
        #pragma unroll
        for (int ks = 0; ks < 8; ++ks) {
            f32x4 v0 = *(const f32x4*)(baseI + ks * 16);
            f32x4 v1 = *(const f32x4*)(baseI + ks * 16 + 4);
            f32x4 w0 = *(const f32x4*)(baseV + ks * 16);
            f32x4 w1 = *(const f32x4*)(baseV + ks * 16 + 4);
            bf16x8 a, b;
            #pragma unroll
            for (int j = 0; j < 4; ++j) {
                a[j] = (__bf16)v0[j]; a[j + 4] = (__bf16)v1[j];
                b[j] = (__bf16)w0[j]; b[j + 4] = (__bf16)w1[j];
            }
            tI[ks] = a;
            tV[ks] = b;
        }
    }
    __syncthreads();

    const bf16x8* fragI = (const bf16x8*)(const void*)sFI;
    const bf16x8* fragV = (const bf16x8*)(const void*)sFV;

    // ---- nt-loop: 32 weight-cols (2 d's x 16 ranks) per MFMA set ----
    float seqv[FUSED];
    #pragma unroll
    for (int nt = 0; nt < 5; ++nt) {
        f32x16 accU = {};
        f32x16 accV = {};
        #pragma unroll
        for (int ks = 0; ks < 8; ++ks) {
            accU = __builtin_amdgcn_mfma_f32_32x32x16_bf16(fragI[(nt * 8 + ks) * 64 + lane], tI[ks], accU, 0, 0, 0);
            accV = __builtin_amdgcn_mfma_f32_32x32x16_bf16(fragV[(nt * 8 + ks) * 64 + lane], tV[ks], accV, 0, 0, 0);
        }
        // acc row m=(reg&3)+8*(reg>>2)+4*hi: regs 0-7 -> d=nt*2, regs 8-15 -> d=nt*2+1
        f32x4 a00 = *(const f32x4*)(sA0 + nt * 32 + hi * 8);        // dl=0 slots 0-3
        f32x4 a01 = *(const f32x4*)(sA0 + nt * 32 + hi * 8 + 4);    // dl=0 slots 4-7
        f32x4 a10 = *(const f32x4*)(sA0 + nt * 32 + 16 + hi * 8);
        f32x4 a11 = *(const f32x4*)(sA0 + nt * 32 + 16 + hi * 8 + 4);
        f32x4 b00 = *(const f32x4*)(sB0 + nt * 32 + hi * 8);
        f32x4 b01 = *(const f32x4*)(sB0 + nt * 32 + hi * 8 + 4);
        f32x4 b10 = *(const f32x4*)(sB0 + nt * 32 + 16 + hi * 8);
        f32x4 b11 = *(const f32x4*)(sB0 + nt * 32 + 16 + hi * 8 + 4);
        float s0 = 0.f, s1 = 0.f;
        #pragma unroll
        for (int q = 0; q < 4; ++q) {
            s0 += (accU[q]      + a00[q]) * (accV[q]      + b00[q]);
            s0 += (accU[q + 4]  + a01[q]) * (accV[q + 4]  + b01[q]);
            s1 += (accU[q + 8]  + a10[q]) * (accV[q + 8]  + b10[q]);
            s1 += (accU[q + 12] + a11[q]) * (accV[q + 12] + b11[q]);
        }
        s0 += __shfl_xor(s0, 32, 64);    // combine rank-halves across hi
        s1 += __shfl_xor(s1, 32, 64);
        seqv[nt * 2]     = s0;           // seq[token=col][d]
        seqv[nt * 2 + 1] = s1;
    }

    // ---- MLP: lane = token col, j-half = hi (64 j's per lane) ----
    float o0 = 0.f, o1 = 0.f;
    #pragma unroll
    for (int jg = 0; jg < 16; ++jg) {
        const int gq = hi * 16 + jg;
        f32x4 h = *(const f32x4*)(sB1L + gq * 4);
        #pragma unroll
        for (int d = 0; d < FUSED; ++d) {
            f32x4 wv = *(const f32x4*)(sW1L + (gq * 10 + d) * 4);
            #pragma unroll
            for (int i = 0; i < 4; ++i) h[i] += seqv[d] * wv[i];
        }
        f32x4 w20v = *(const f32x4*)(sW20 + gq * 4);
        f32x4 w21v = *(const f32x4*)(sW21 + gq * 4);
        #pragma unroll
        for (int i = 0; i < 4; ++i) {
            float hr = fmaxf(h[i], 0.f);
            o0 += hr * w20v[i];
            o1 += hr * w21v[i];
        }
    }
    o0 += __shfl_xor(o0, 32, 64);        // combine j-halves
    o1 += __shfl_xor(o1, 32, 64);

    if (hi == 0) {                       // lanes 0-31: 32 tokens, 256B contiguous
        const int t = t0 + col;
        float2 o = make_float2((o0 + b20) * invwh, (o1 + b21) * invwh);
        *(float2*)(out + 2 * t) = o;
    }
}

// ---------------------------------------------------------------------------
extern "C" void kernel_launch(void* const* d_in, const int* in_sizes, int n_in,
                              void* d_out, int out_size, void* d_ws, size_t ws_size,
                              hipStream_t stream) {
    const float* imu    = (const float*)d_in[0];
    const float* vid    = (const float*)d_in[1];
    const float* anthro = (const float*)d_in[2];
    const float* imf    = (const float*)d_in[3];
    const float* vif    = (const float*)d_in[4];
    const float* fw     = (const float*)d_in[5];
    const float* fb     = (const float*)d_in[6];
    const float* W1     = (const float*)d_in[7];
    const float* b1     = (const float*)d_in[8];
    const float* W2     = (const float*)d_in[9];
    const float* b2     = (const float*)d_in[10];
    float* out = (float*)d_out;

    // workspace: [wImu u16 20480][wVid u16 20480][extras f32 1984]
    u16* wImu = (u16*)d_ws;
    u16* wVid = wImu + WTE;
    float* extra = (float*)(wVid + WTE);

    prep_kernel<<<80, 256, 0, stream>>>(imf, vif, fw, fb, W1, b1, W2,
                                        wImu, wVid, extra);

    const size_t smem = (size_t)(2 * WTE) * sizeof(u16)
                      + (size_t)NEXTRA * sizeof(float);    // 89856 B
    // 1024 blocks x 8 waves x 32 tokens = 262144 tokens exactly
    fusion_main<<<1024, 512, smem, stream>>>(imu, vid, anthro, wImu, wVid,
                                             extra, b2, out);
}